// Round 1
// baseline (722.499 us; speedup 1.0000x reference)
//
#include <hip/hip_runtime.h>

typedef float f32x4 __attribute__((ext_vector_type(4)));
typedef short s16x8 __attribute__((ext_vector_type(8)));
typedef unsigned short ushort_t;

__device__ __forceinline__ unsigned short f2bf(float f) {
    union { float f; unsigned int u; } v; v.f = f;
    unsigned int r = (v.u + 0x7fffu + ((v.u >> 16) & 1u)) >> 16;
    return (unsigned short)r;
}

__device__ __forceinline__ f32x4 mfma_bf16(s16x8 a, s16x8 b, f32x4 c) {
    return __builtin_amdgcn_mfma_f32_16x16x32_bf16(a, b, c, 0, 0, 0);
}

// ---------------------------------------------------------------------------
// Kernel 1: QKV projection. y = relu(x @ W^T + b)  (q additionally * 1/sqrt(512))
// x: [8192,512] f32, W: [512,512] f32 (row-major [e][d] -> B^T GEMM), out bf16.
// Tile: BM=128, BN=128, BK=32. 4 waves in 2x2, each wave 64x64 (4x4 MFMA frags).
// grid = (64 m-tiles, 4 n-tiles, 3 weights)
// ---------------------------------------------------------------------------
#define PLDK 40  // padded K cols in LDS (bf16 elems); row stride 80B (16B aligned, 2-way banks)

__global__ __launch_bounds__(256) void qkv_proj(
    const float* __restrict__ x,
    const float* __restrict__ Wq, const float* __restrict__ bq,
    const float* __restrict__ Wk, const float* __restrict__ bk,
    const float* __restrict__ Wv, const float* __restrict__ bv,
    ushort_t* __restrict__ qkv_ws)
{
    const int mblk  = blockIdx.x;
    const int nblk  = blockIdx.y;
    const int which = blockIdx.z;

    const float* W    = (which == 0) ? Wq : (which == 1) ? Wk : Wv;
    const float* bias = (which == 0) ? bq : (which == 1) ? bk : bv;
    ushort_t* out = qkv_ws + (size_t)which * (8192u * 512u);
    const float scale = (which == 0) ? 0.04419417382415922f : 1.0f;  // 1/sqrt(512)

    __shared__ ushort_t a_lds[128][PLDK];
    __shared__ ushort_t b_lds[128][PLDK];

    const int tid  = threadIdx.x;
    const int lane = tid & 63;
    const int wave = tid >> 6;
    const int wr = wave >> 1, wc = wave & 1;

    const int srow = tid >> 1;          // staging: row 0..127
    const int scol = (tid & 1) * 16;    // staging: col 0 or 16

    f32x4 acc[4][4] = {};

    for (int k0 = 0; k0 < 512; k0 += 32) {
        // stage A (x) fp32 -> bf16
        {
            const float* src = x + (size_t)(mblk * 128 + srow) * 512 + k0 + scol;
            ushort_t tmp[16];
            #pragma unroll
            for (int i = 0; i < 16; i++) tmp[i] = f2bf(src[i]);
            #pragma unroll
            for (int i = 0; i < 16; i++) a_lds[srow][scol + i] = tmp[i];
        }
        // stage B (W) fp32 -> bf16
        {
            const float* src = W + (size_t)(nblk * 128 + srow) * 512 + k0 + scol;
            ushort_t tmp[16];
            #pragma unroll
            for (int i = 0; i < 16; i++) tmp[i] = f2bf(src[i]);
            #pragma unroll
            for (int i = 0; i < 16; i++) b_lds[srow][scol + i] = tmp[i];
        }
        __syncthreads();

        s16x8 af[4], bf[4];
        #pragma unroll
        for (int m = 0; m < 4; m++)
            af[m] = *reinterpret_cast<const s16x8*>(&a_lds[wr * 64 + m * 16 + (lane & 15)][(lane >> 4) * 8]);
        #pragma unroll
        for (int n = 0; n < 4; n++)
            bf[n] = *reinterpret_cast<const s16x8*>(&b_lds[wc * 64 + n * 16 + (lane & 15)][(lane >> 4) * 8]);

        #pragma unroll
        for (int m = 0; m < 4; m++)
            #pragma unroll
            for (int n = 0; n < 4; n++)
                acc[m][n] = mfma_bf16(af[m], bf[n], acc[m][n]);

        __syncthreads();
    }

    // epilogue: bias + relu + scale -> bf16
    #pragma unroll
    for (int n = 0; n < 4; n++) {
        const int col = nblk * 128 + wc * 64 + n * 16 + (lane & 15);
        const float b = bias[col];
        #pragma unroll
        for (int m = 0; m < 4; m++) {
            #pragma unroll
            for (int j = 0; j < 4; j++) {
                const int row = mblk * 128 + wr * 64 + m * 16 + (lane >> 4) * 4 + j;
                float v = acc[m][n][j] + b;
                v = fmaxf(v, 0.0f) * scale;
                out[(size_t)row * 512 + col] = f2bf(v);
            }
        }
    }
}

// ---------------------------------------------------------------------------
// Kernel 2: flash attention. Block = 4 waves x 16 q-rows = 64 rows, full D=512.
// K/V tile = 32 keys staged in LDS (V transposed). Online softmax.
// grid = (4096/64 = 64, B = 2)
// ---------------------------------------------------------------------------
__global__ __launch_bounds__(256, 1) void attn_kernel(
    const ushort_t* __restrict__ qkv_ws, float* __restrict__ out)
{
    const int qblk  = blockIdx.x;
    const int batch = blockIdx.y;
    const int tid = threadIdx.x, lane = tid & 63, wave = tid >> 6;

    const ushort_t* q_ws = qkv_ws;
    const ushort_t* k_ws = qkv_ws + (size_t)8192 * 512;
    const ushort_t* v_ws = qkv_ws + (size_t)2 * 8192 * 512;
    const size_t base = (size_t)batch * 4096 * 512;

    __shared__ ushort_t k_lds[32][520];   // [t][d], padded (row 1040B, 16B-aligned)
    __shared__ ushort_t vt_lds[512][40];  // [d][t], padded (row 80B)
    __shared__ ushort_t p_lds[4][16][40]; // per-wave P bounce buffer

    // resident Q fragments: 16 k-steps x 8 bf16
    s16x8 qf[16];
    {
        const int qrow = qblk * 64 + wave * 16 + (lane & 15);
        const ushort_t* qp = q_ws + base + (size_t)qrow * 512 + (lane >> 4) * 8;
        #pragma unroll
        for (int ks = 0; ks < 16; ks++)
            qf[ks] = *reinterpret_cast<const s16x8*>(qp + ks * 32);
    }

    const f32x4 zf = {0.f, 0.f, 0.f, 0.f};
    f32x4 o[32];
    #pragma unroll
    for (int n = 0; n < 32; n++) o[n] = zf;
    float mrow[4], lrow[4];
    #pragma unroll
    for (int j = 0; j < 4; j++) { mrow[j] = -1e30f; lrow[j] = 0.0f; }

    for (int it = 0; it < 128; ++it) {
        const int kv0 = it * 32;
        // ---- stage K tile [32][512]
        {
            const int trow = tid >> 3, d0 = (tid & 7) * 64;
            const ushort_t* src = k_ws + base + (size_t)(kv0 + trow) * 512 + d0;
            #pragma unroll
            for (int i = 0; i < 8; i++)
                *reinterpret_cast<s16x8*>(&k_lds[trow][d0 + i * 8]) =
                    *reinterpret_cast<const s16x8*>(src + i * 8);
        }
        // ---- stage V transposed: vt[d][t]
        {
            const int trow = tid & 31, d0 = (tid >> 5) * 64;
            const ushort_t* src = v_ws + base + (size_t)(kv0 + trow) * 512 + d0;
            #pragma unroll
            for (int i = 0; i < 8; i++) {
                s16x8 v = *reinterpret_cast<const s16x8*>(src + i * 8);
                #pragma unroll
                for (int e = 0; e < 8; e++)
                    vt_lds[d0 + i * 8 + e][trow] = (ushort_t)v[e];
            }
        }
        __syncthreads();

        // ---- QK^T : S[16 rows][32 keys], fp32 accum
        f32x4 s0 = zf, s1 = zf;
        #pragma unroll
        for (int ks = 0; ks < 16; ++ks) {
            const s16x8 kf0 = *reinterpret_cast<const s16x8*>(
                &k_lds[lane & 15][ks * 32 + (lane >> 4) * 8]);
            s0 = mfma_bf16(qf[ks], kf0, s0);
            const s16x8 kf1 = *reinterpret_cast<const s16x8*>(
                &k_lds[16 + (lane & 15)][ks * 32 + (lane >> 4) * 8]);
            s1 = mfma_bf16(qf[ks], kf1, s1);
        }

        // ---- online softmax chunk (rows live at (lane>>4)*4+j, cols at lane&15 +16*n16)
        float fac[4], p0[4], p1[4];
        #pragma unroll
        for (int j = 0; j < 4; j++) {
            float mt = fmaxf(s0[j], s1[j]);
            #pragma unroll
            for (int msk = 8; msk >= 1; msk >>= 1) mt = fmaxf(mt, __shfl_xor(mt, msk, 64));
            const float mn = fmaxf(mrow[j], mt);
            fac[j] = __expf(mrow[j] - mn);
            mrow[j] = mn;
            p0[j] = __expf(s0[j] - mn);
            p1[j] = __expf(s1[j] - mn);
            float rs = p0[j] + p1[j];
            #pragma unroll
            for (int msk = 8; msk >= 1; msk >>= 1) rs += __shfl_xor(rs, msk, 64);
            lrow[j] = lrow[j] * fac[j] + rs;
        }

        // ---- P -> bf16 via per-wave LDS bounce (to MFMA A-frag layout)
        #pragma unroll
        for (int j = 0; j < 4; j++) {
            const int prow = (lane >> 4) * 4 + j;
            p_lds[wave][prow][lane & 15] = f2bf(p0[j]);
            p_lds[wave][prow][16 + (lane & 15)] = f2bf(p1[j]);
        }

        // ---- rescale O by exp(m_old - m_new) per row
        #pragma unroll
        for (int n = 0; n < 32; n++)
            #pragma unroll
            for (int j = 0; j < 4; j++) o[n][j] *= fac[j];

        const s16x8 pf = *reinterpret_cast<const s16x8*>(
            &p_lds[wave][lane & 15][(lane >> 4) * 8]);

        // ---- PV: O[16][512] += P[16][32] @ V[32][512]
        #pragma unroll
        for (int n = 0; n < 32; n++) {
            const s16x8 vf = *reinterpret_cast<const s16x8*>(
                &vt_lds[n * 16 + (lane & 15)][(lane >> 4) * 8]);
            o[n] = mfma_bf16(pf, vf, o[n]);
        }
        __syncthreads();
    }

    // ---- epilogue: divide by l, write fp32
    float inv[4];
    #pragma unroll
    for (int j = 0; j < 4; j++) inv[j] = 1.0f / lrow[j];
    const int qrowb = qblk * 64 + wave * 16;
    #pragma unroll
    for (int n = 0; n < 32; n++) {
        #pragma unroll
        for (int j = 0; j < 4; j++) {
            const int row = qrowb + (lane >> 4) * 4 + j;
            out[base + (size_t)row * 512 + n * 16 + (lane & 15)] = o[n][j] * inv[j];
        }
    }
}

extern "C" void kernel_launch(void* const* d_in, const int* in_sizes, int n_in,
                              void* d_out, int out_size, void* d_ws, size_t ws_size,
                              hipStream_t stream) {
    const float* x  = (const float*)d_in[0];
    const float* Wq = (const float*)d_in[1];
    const float* bq = (const float*)d_in[2];
    const float* Wk = (const float*)d_in[3];
    const float* bk = (const float*)d_in[4];
    const float* Wv = (const float*)d_in[5];
    const float* bv = (const float*)d_in[6];
    float* out = (float*)d_out;
    ushort_t* qkv = (ushort_t*)d_ws;  // q | k | v, each 8192*512 bf16
    (void)in_sizes; (void)n_in; (void)out_size; (void)ws_size;

    dim3 gp(64, 4, 3);
    qkv_proj<<<gp, 256, 0, stream>>>(x, Wq, bq, Wk, bk, Wv, bv, qkv);

    dim3 ga(64, 2);
    attn_kernel<<<ga, 256, 0, stream>>>(qkv, out);
}

// Round 2
// 260.095 us; speedup vs baseline: 2.7778x; 2.7778x over previous
//
#include <hip/hip_runtime.h>

typedef float f32x4 __attribute__((ext_vector_type(4)));
typedef short s16x8 __attribute__((ext_vector_type(8)));
typedef unsigned short u16x4 __attribute__((ext_vector_type(4)));
typedef unsigned short ushort_t;

__device__ __forceinline__ unsigned short f2bf(float f) {
    union { float f; unsigned int u; } v; v.f = f;
    unsigned int r = (v.u + 0x7fffu + ((v.u >> 16) & 1u)) >> 16;
    return (unsigned short)r;
}
__device__ __forceinline__ float bf2f(unsigned short b) {
    union { unsigned int u; float f; } v; v.u = ((unsigned int)b) << 16;
    return v.f;
}

__device__ __forceinline__ f32x4 mfma_bf16(s16x8 a, s16x8 b, f32x4 c) {
    return __builtin_amdgcn_mfma_f32_16x16x32_bf16(a, b, c, 0, 0, 0);
}

__device__ __forceinline__ void gl_lds16(const void* g, void* l) {
    __builtin_amdgcn_global_load_lds(
        (const __attribute__((address_space(1))) unsigned int*)g,
        (__attribute__((address_space(3))) unsigned int*)l, 16, 0, 0);
}

// ---------------------------------------------------------------------------
// Kernel 1: QKV projection. y = relu(x @ W^T + b); q *= 1/sqrt(512).
// q,k written row-major [batch*4096][512]; v written TRANSPOSED [batch][512][4096].
// ---------------------------------------------------------------------------
#define PLDK 40

__global__ __launch_bounds__(256) void qkv_proj(
    const float* __restrict__ x,
    const float* __restrict__ Wq, const float* __restrict__ bq,
    const float* __restrict__ Wk, const float* __restrict__ bk,
    const float* __restrict__ Wv, const float* __restrict__ bv,
    ushort_t* __restrict__ qkv_ws)
{
    const int mblk  = blockIdx.x;
    const int nblk  = blockIdx.y;
    const int which = blockIdx.z;

    const float* W    = (which == 0) ? Wq : (which == 1) ? Wk : Wv;
    const float* bias = (which == 0) ? bq : (which == 1) ? bk : bv;
    ushort_t* out = qkv_ws + (size_t)which * (8192u * 512u);
    const float scale = (which == 0) ? 0.04419417382415922f : 1.0f;  // 1/sqrt(512)

    __shared__ ushort_t a_lds[128][PLDK];
    __shared__ ushort_t b_lds[128][PLDK];

    const int tid  = threadIdx.x;
    const int lane = tid & 63;
    const int wave = tid >> 6;
    const int wr = wave >> 1, wc = wave & 1;

    const int srow = tid >> 1;
    const int scol = (tid & 1) * 16;

    f32x4 acc[4][4] = {};

    for (int k0 = 0; k0 < 512; k0 += 32) {
        {
            const float* src = x + (size_t)(mblk * 128 + srow) * 512 + k0 + scol;
            ushort_t tmp[16];
            #pragma unroll
            for (int i = 0; i < 16; i++) tmp[i] = f2bf(src[i]);
            #pragma unroll
            for (int i = 0; i < 16; i++) a_lds[srow][scol + i] = tmp[i];
        }
        {
            const float* src = W + (size_t)(nblk * 128 + srow) * 512 + k0 + scol;
            ushort_t tmp[16];
            #pragma unroll
            for (int i = 0; i < 16; i++) tmp[i] = f2bf(src[i]);
            #pragma unroll
            for (int i = 0; i < 16; i++) b_lds[srow][scol + i] = tmp[i];
        }
        __syncthreads();

        s16x8 af[4], bf[4];
        #pragma unroll
        for (int m = 0; m < 4; m++)
            af[m] = *reinterpret_cast<const s16x8*>(&a_lds[wr * 64 + m * 16 + (lane & 15)][(lane >> 4) * 8]);
        #pragma unroll
        for (int n = 0; n < 4; n++)
            bf[n] = *reinterpret_cast<const s16x8*>(&b_lds[wc * 64 + n * 16 + (lane & 15)][(lane >> 4) * 8]);

        #pragma unroll
        for (int m = 0; m < 4; m++)
            #pragma unroll
            for (int n = 0; n < 4; n++)
                acc[m][n] = mfma_bf16(af[m], bf[n], acc[m][n]);

        __syncthreads();
    }

    if (which == 2) {
        // V: transposed store vt[batch][d=512][4096]
        #pragma unroll
        for (int n = 0; n < 4; n++) {
            const int col = nblk * 128 + wc * 64 + n * 16 + (lane & 15);
            const float b = bias[col];
            #pragma unroll
            for (int m = 0; m < 4; m++) {
                const int rowb = mblk * 128 + wr * 64 + m * 16 + (lane >> 4) * 4;
                const int batch = rowb >> 12, sr = rowb & 4095;
                u16x4 pk;
                #pragma unroll
                for (int j = 0; j < 4; j++)
                    pk[j] = f2bf(fmaxf(acc[m][n][j] + b, 0.0f));
                *reinterpret_cast<u16x4*>(out + (size_t)batch * 512 * 4096 +
                                          (size_t)col * 4096 + sr) = pk;
            }
        }
    } else {
        #pragma unroll
        for (int n = 0; n < 4; n++) {
            const int col = nblk * 128 + wc * 64 + n * 16 + (lane & 15);
            const float b = bias[col];
            #pragma unroll
            for (int m = 0; m < 4; m++) {
                #pragma unroll
                for (int j = 0; j < 4; j++) {
                    const int row = mblk * 128 + wr * 64 + m * 16 + (lane >> 4) * 4 + j;
                    float v = fmaxf(acc[m][n][j] + b, 0.0f) * scale;
                    out[(size_t)row * 512 + col] = f2bf(v);
                }
            }
        }
    }
}

// ---------------------------------------------------------------------------
// Kernel 2: flash attention, KV-split. Block = 4 waves x 16 q-rows.
// K tile [32][512] and V^T tile [512][32] staged via global_load_lds with
// XOR-swizzled addressing. grid = (2*SP combos, 64 qblks).
// Partial (m,l,O-bf16) to ws unless opart==nullptr (direct f32 out).
// ---------------------------------------------------------------------------
__global__ __launch_bounds__(256, 2) void attn_v2(
    const ushort_t* __restrict__ qkv_ws,
    ushort_t* __restrict__ opart, float* __restrict__ ml,
    float* __restrict__ out, int SP, int NK)
{
    const int combo = blockIdx.x;
    const int batch = combo / SP;
    const int split = combo % SP;
    const int qblk  = blockIdx.y;
    const int tid = threadIdx.x, lane = tid & 63, wave = tid >> 6;
    const int kv00 = split * (4096 / SP);

    const ushort_t* q_ws  = qkv_ws;
    const ushort_t* k_ws  = qkv_ws + (size_t)8192 * 512;
    const ushort_t* vt_ws = qkv_ws + (size_t)2 * 8192 * 512;  // [batch][512][4096]
    const size_t base  = (size_t)batch * 4096 * 512;
    const size_t vbase = (size_t)batch * 512 * 4096;

    __shared__ ushort_t k_lds[32 * 512];    // 32KB, swizzled
    __shared__ ushort_t vt_lds[512 * 32];   // 32KB, swizzled
    __shared__ ushort_t p_lds[4][16][40];

    // resident Q fragments
    s16x8 qf[16];
    {
        const int qrow = qblk * 64 + wave * 16 + (lane & 15);
        const ushort_t* qp = q_ws + base + (size_t)qrow * 512 + (lane >> 4) * 8;
        #pragma unroll
        for (int ks = 0; ks < 16; ks++)
            qf[ks] = *reinterpret_cast<const s16x8*>(qp + ks * 32);
    }

    const f32x4 zf = {0.f, 0.f, 0.f, 0.f};
    f32x4 o[32];
    #pragma unroll
    for (int n = 0; n < 32; n++) o[n] = zf;
    float mrow[4], lrow[4];
    #pragma unroll
    for (int j = 0; j < 4; j++) { mrow[j] = -1e30f; lrow[j] = 0.0f; }

    const int g = lane >> 4;

    for (int it = 0; it < NK; ++it) {
        const int kv0 = kv00 + it * 32;

        // ---- stage K tile: linear LDS dest, inverse-swizzled global src
        #pragma unroll
        for (int i = 0; i < 8; i++) {
            const int C   = i * 4096 + tid * 16;        // dest byte in tile
            const int row = C >> 10;                    // key 0..31
            const int Lc  = (C & 1023) ^ ((row & 7) << 4);
            gl_lds16(k_ws + base + (size_t)(kv0 + row) * 512 + (Lc >> 1),
                     (char*)k_lds + C);
        }
        // ---- stage V^T tile
        #pragma unroll
        for (int i = 0; i < 8; i++) {
            const int C    = i * 4096 + tid * 16;
            const int drow = C >> 6;                    // d 0..511
            const int gc   = (C >> 4) & 3;
            const int gl   = gc ^ ((drow >> 1) & 3);
            gl_lds16(vt_ws + vbase + (size_t)drow * 4096 + kv0 + gl * 8,
                     (char*)vt_lds + C);
        }
        __syncthreads();

        // ---- QK^T : S[16 rows][32 keys]
        f32x4 s0 = zf, s1 = zf;
        #pragma unroll
        for (int ks = 0; ks < 16; ++ks) {
            const int key0 = lane & 15;
            const s16x8 kf0 = *reinterpret_cast<const s16x8*>(
                (const char*)k_lds + key0 * 1024 + ((ks * 64 + g * 16) ^ ((key0 & 7) << 4)));
            s0 = mfma_bf16(qf[ks], kf0, s0);
            const int key1 = 16 + (lane & 15);
            const s16x8 kf1 = *reinterpret_cast<const s16x8*>(
                (const char*)k_lds + key1 * 1024 + ((ks * 64 + g * 16) ^ ((key1 & 7) << 4)));
            s1 = mfma_bf16(qf[ks], kf1, s1);
        }

        // ---- online softmax
        float fac[4], p0[4], p1[4];
        #pragma unroll
        for (int j = 0; j < 4; j++) {
            float mt = fmaxf(s0[j], s1[j]);
            #pragma unroll
            for (int msk = 8; msk >= 1; msk >>= 1) mt = fmaxf(mt, __shfl_xor(mt, msk, 64));
            const float mn = fmaxf(mrow[j], mt);
            fac[j] = __expf(mrow[j] - mn);
            mrow[j] = mn;
            p0[j] = __expf(s0[j] - mn);
            p1[j] = __expf(s1[j] - mn);
            float rs = p0[j] + p1[j];
            #pragma unroll
            for (int msk = 8; msk >= 1; msk >>= 1) rs += __shfl_xor(rs, msk, 64);
            lrow[j] = lrow[j] * fac[j] + rs;
        }

        // ---- P -> bf16 via per-wave LDS bounce
        #pragma unroll
        for (int j = 0; j < 4; j++) {
            const int prow = g * 4 + j;
            p_lds[wave][prow][lane & 15] = f2bf(p0[j]);
            p_lds[wave][prow][16 + (lane & 15)] = f2bf(p1[j]);
        }

        // ---- rescale O
        #pragma unroll
        for (int n = 0; n < 32; n++)
            #pragma unroll
            for (int j = 0; j < 4; j++) o[n][j] *= fac[j];

        const s16x8 pf = *reinterpret_cast<const s16x8*>(
            &p_lds[wave][lane & 15][g * 8]);

        // ---- PV: O[16][512] += P[16][32] @ V[32][512]
        #pragma unroll
        for (int n = 0; n < 32; n++) {
            const int d = n * 16 + (lane & 15);
            const s16x8 vf = *reinterpret_cast<const s16x8*>(
                (const char*)vt_lds + d * 64 + ((g * 16) ^ (((d >> 1) & 3) << 4)));
            o[n] = mfma_bf16(pf, vf, o[n]);
        }
        __syncthreads();
    }

    // ---- epilogue
    if (opart != nullptr) {
        const int qrowb = qblk * 64 + wave * 16;
        const size_t prow8k = (size_t)batch * 4096;
        #pragma unroll
        for (int j = 0; j < 4; j++) {
            const int rib = qrowb + g * 4 + j;
            if ((lane & 15) == 0) {
                const size_t r8 = prow8k + rib;
                ml[((size_t)split * 8192 + r8) * 2]     = mrow[j];
                ml[((size_t)split * 8192 + r8) * 2 + 1] = lrow[j];
            }
        }
        ushort_t* op = opart + (size_t)split * 8192 * 512;
        #pragma unroll
        for (int n = 0; n < 32; n++) {
            #pragma unroll
            for (int j = 0; j < 4; j++) {
                const size_t r8 = prow8k + qrowb + g * 4 + j;
                op[r8 * 512 + n * 16 + (lane & 15)] = f2bf(o[n][j]);
            }
        }
    } else {
        float inv[4];
        #pragma unroll
        for (int j = 0; j < 4; j++) inv[j] = 1.0f / lrow[j];
        const int qrowb = qblk * 64 + wave * 16;
        #pragma unroll
        for (int n = 0; n < 32; n++) {
            #pragma unroll
            for (int j = 0; j < 4; j++) {
                const int row = qrowb + g * 4 + j;
                out[base + (size_t)row * 512 + n * 16 + (lane & 15)] = o[n][j] * inv[j];
            }
        }
    }
}

// ---------------------------------------------------------------------------
// Kernel 3: merge KV-split partials. 1 wave per row, 4 rows per block.
// ---------------------------------------------------------------------------
__global__ __launch_bounds__(256) void merge_kernel(
    const ushort_t* __restrict__ opart, const float* __restrict__ ml,
    float* __restrict__ out, int SP)
{
    const int row  = blockIdx.x * 4 + (threadIdx.x >> 6);
    const int lane = threadIdx.x & 63;

    float M = -1e30f;
    for (int s = 0; s < SP; s++)
        M = fmaxf(M, ml[((size_t)s * 8192 + row) * 2]);
    float denom = 0.0f, w[4];
    for (int s = 0; s < SP; s++) {
        w[s] = __expf(ml[((size_t)s * 8192 + row) * 2] - M);
        denom += w[s] * ml[((size_t)s * 8192 + row) * 2 + 1];
    }
    const float inv = 1.0f / denom;

    float acc[8] = {};
    for (int s = 0; s < SP; s++) {
        const s16x8 v = *reinterpret_cast<const s16x8*>(
            opart + ((size_t)s * 8192 + row) * 512 + lane * 8);
        #pragma unroll
        for (int i = 0; i < 8; i++)
            acc[i] += w[s] * bf2f((ushort_t)v[i]);
    }
    float* dst = out + (size_t)row * 512 + lane * 8;
    #pragma unroll
    for (int i = 0; i < 8; i++) dst[i] = acc[i] * inv;
}

extern "C" void kernel_launch(void* const* d_in, const int* in_sizes, int n_in,
                              void* d_out, int out_size, void* d_ws, size_t ws_size,
                              hipStream_t stream) {
    const float* x  = (const float*)d_in[0];
    const float* Wq = (const float*)d_in[1];
    const float* bq = (const float*)d_in[2];
    const float* Wk = (const float*)d_in[3];
    const float* bk = (const float*)d_in[4];
    const float* Wv = (const float*)d_in[5];
    const float* bv = (const float*)d_in[6];
    float* out = (float*)d_out;
    ushort_t* qkv = (ushort_t*)d_ws;  // q | k | vt, each 8192*512 bf16
    (void)in_sizes; (void)n_in; (void)out_size;

    const size_t qkv_bytes = 3ull * 8192 * 512 * 2;  // 25165824

    int SP = 0;  // 0 => direct mode (no partials)
    if (ws_size >= qkv_bytes + 4ull * (8388608 + 65536)) SP = 4;
    else if (ws_size >= qkv_bytes + 2ull * (8388608 + 65536)) SP = 2;
    else if (ws_size >= qkv_bytes + 1ull * (8388608 + 65536)) SP = 1;

    dim3 gp(64, 4, 3);
    qkv_proj<<<gp, 256, 0, stream>>>(x, Wq, bq, Wk, bk, Wv, bv, qkv);

    if (SP > 0) {
        ushort_t* opart = qkv + 3ull * 8192 * 512;
        float* ml = (float*)(opart + (size_t)SP * 8192 * 512);
        dim3 ga(2 * SP, 64);
        attn_v2<<<ga, 256, 0, stream>>>(qkv, opart, ml, out, SP, 4096 / SP / 32);
        merge_kernel<<<2048, 256, 0, stream>>>(opart, ml, out, SP);
    } else {
        dim3 ga(2, 64);
        attn_v2<<<ga, 256, 0, stream>>>(qkv, nullptr, nullptr, out, 1, 128);
    }
}

// Round 3
// 216.885 us; speedup vs baseline: 3.3313x; 1.1992x over previous
//
#include <hip/hip_runtime.h>

typedef float f32x4 __attribute__((ext_vector_type(4)));
typedef short s16x8 __attribute__((ext_vector_type(8)));
typedef unsigned short u16x4 __attribute__((ext_vector_type(4)));
typedef unsigned short ushort_t;

__device__ __forceinline__ unsigned short f2bf(float f) {
    union { float f; unsigned int u; } v; v.f = f;
    unsigned int r = (v.u + 0x7fffu + ((v.u >> 16) & 1u)) >> 16;
    return (unsigned short)r;
}
__device__ __forceinline__ float bf2f(unsigned short b) {
    union { unsigned int u; float f; } v; v.u = ((unsigned int)b) << 16;
    return v.f;
}

__device__ __forceinline__ f32x4 mfma_bf16(s16x8 a, s16x8 b, f32x4 c) {
    return __builtin_amdgcn_mfma_f32_16x16x32_bf16(a, b, c, 0, 0, 0);
}

__device__ __forceinline__ void gl_lds16(const void* g, void* l) {
    __builtin_amdgcn_global_load_lds(
        (const __attribute__((address_space(1))) unsigned int*)g,
        (__attribute__((address_space(3))) unsigned int*)l, 16, 0, 0);
}

// log2(e)/sqrt(512): fold exp->exp2 conversion into Q scale
#define QSCALE 0.06375871469f
#define DEFER_THR 11.5416f   // 8 nats in log2 units

// ---------------------------------------------------------------------------
// Kernel 1: QKV projection. y = relu(x @ W^T + b); q *= log2(e)/sqrt(512).
// q,k row-major [batch*4096][512]; v TRANSPOSED [batch][512][4096].
// ---------------------------------------------------------------------------
#define PLDK 40

__global__ __launch_bounds__(256) void qkv_proj(
    const float* __restrict__ x,
    const float* __restrict__ Wq, const float* __restrict__ bq,
    const float* __restrict__ Wk, const float* __restrict__ bk,
    const float* __restrict__ Wv, const float* __restrict__ bv,
    ushort_t* __restrict__ qkv_ws)
{
    const int mblk  = blockIdx.x;
    const int nblk  = blockIdx.y;
    const int which = blockIdx.z;

    const float* W    = (which == 0) ? Wq : (which == 1) ? Wk : Wv;
    const float* bias = (which == 0) ? bq : (which == 1) ? bk : bv;
    ushort_t* out = qkv_ws + (size_t)which * (8192u * 512u);
    const float scale = (which == 0) ? QSCALE : 1.0f;

    __shared__ ushort_t a_lds[128][PLDK];
    __shared__ ushort_t b_lds[128][PLDK];

    const int tid  = threadIdx.x;
    const int lane = tid & 63;
    const int wave = tid >> 6;
    const int wr = wave >> 1, wc = wave & 1;

    const int srow = tid >> 1;
    const int scol = (tid & 1) * 16;

    f32x4 acc[4][4] = {};

    for (int k0 = 0; k0 < 512; k0 += 32) {
        {
            const float* src = x + (size_t)(mblk * 128 + srow) * 512 + k0 + scol;
            ushort_t tmp[16];
            #pragma unroll
            for (int i = 0; i < 16; i++) tmp[i] = f2bf(src[i]);
            #pragma unroll
            for (int i = 0; i < 16; i++) a_lds[srow][scol + i] = tmp[i];
        }
        {
            const float* src = W + (size_t)(nblk * 128 + srow) * 512 + k0 + scol;
            ushort_t tmp[16];
            #pragma unroll
            for (int i = 0; i < 16; i++) tmp[i] = f2bf(src[i]);
            #pragma unroll
            for (int i = 0; i < 16; i++) b_lds[srow][scol + i] = tmp[i];
        }
        __syncthreads();

        s16x8 af[4], bf[4];
        #pragma unroll
        for (int m = 0; m < 4; m++)
            af[m] = *reinterpret_cast<const s16x8*>(&a_lds[wr * 64 + m * 16 + (lane & 15)][(lane >> 4) * 8]);
        #pragma unroll
        for (int n = 0; n < 4; n++)
            bf[n] = *reinterpret_cast<const s16x8*>(&b_lds[wc * 64 + n * 16 + (lane & 15)][(lane >> 4) * 8]);

        #pragma unroll
        for (int m = 0; m < 4; m++)
            #pragma unroll
            for (int n = 0; n < 4; n++)
                acc[m][n] = mfma_bf16(af[m], bf[n], acc[m][n]);

        __syncthreads();
    }

    if (which == 2) {
        #pragma unroll
        for (int n = 0; n < 4; n++) {
            const int col = nblk * 128 + wc * 64 + n * 16 + (lane & 15);
            const float b = bias[col];
            #pragma unroll
            for (int m = 0; m < 4; m++) {
                const int rowb = mblk * 128 + wr * 64 + m * 16 + (lane >> 4) * 4;
                const int batch = rowb >> 12, sr = rowb & 4095;
                u16x4 pk;
                #pragma unroll
                for (int j = 0; j < 4; j++)
                    pk[j] = f2bf(fmaxf(acc[m][n][j] + b, 0.0f));
                *reinterpret_cast<u16x4*>(out + (size_t)batch * 512 * 4096 +
                                          (size_t)col * 4096 + sr) = pk;
            }
        }
    } else {
        #pragma unroll
        for (int n = 0; n < 4; n++) {
            const int col = nblk * 128 + wc * 64 + n * 16 + (lane & 15);
            const float b = bias[col];
            #pragma unroll
            for (int m = 0; m < 4; m++) {
                #pragma unroll
                for (int j = 0; j < 4; j++) {
                    const int row = mblk * 128 + wr * 64 + m * 16 + (lane >> 4) * 4 + j;
                    float v = fmaxf(acc[m][n][j] + b, 0.0f) * scale;
                    out[(size_t)row * 512 + col] = f2bf(v);
                }
            }
        }
    }
}

// ---------------------------------------------------------------------------
// Kernel 2: flash attention, 2-phase double-buffered pipeline.
// Block = 8 waves x 16 q-rows = 128 rows, 512 threads. KV tile = 32.
// grid = (2*SP, 32) = 256 blocks at SP=4 -> exactly 1 block/CU.
// ---------------------------------------------------------------------------
__global__ __launch_bounds__(512, 2) void attn_v3(
    const ushort_t* __restrict__ qkv_ws,
    ushort_t* __restrict__ opart, float* __restrict__ ml,
    float* __restrict__ out, int SP, int NK)
{
    const int combo = blockIdx.x;
    const int batch = combo / SP;
    const int split = combo % SP;
    const int qblk  = blockIdx.y;
    const int tid = threadIdx.x, lane = tid & 63, wave = tid >> 6;
    const int kv00 = split * (4096 / SP);

    const ushort_t* q_ws  = qkv_ws;
    const ushort_t* k_ws  = qkv_ws + (size_t)8192 * 512;
    const ushort_t* vt_ws = qkv_ws + (size_t)2 * 8192 * 512;  // [batch][512][4096]
    const size_t base  = (size_t)batch * 4096 * 512;
    const size_t vbase = (size_t)batch * 512 * 4096;

    __shared__ ushort_t k_lds[2][32 * 512];    // 2 x 32KB, swizzled
    __shared__ ushort_t vt_lds[2][512 * 32];   // 2 x 32KB, swizzled
    __shared__ ushort_t p_lds[8][16][40];

    // resident Q fragments (16 k-steps x 8 bf16)
    s16x8 qf[16];
    {
        const int qrow = qblk * 128 + wave * 16 + (lane & 15);
        const ushort_t* qp = q_ws + base + (size_t)qrow * 512 + (lane >> 4) * 8;
        #pragma unroll
        for (int ks = 0; ks < 16; ks++)
            qf[ks] = *reinterpret_cast<const s16x8*>(qp + ks * 32);
    }

    const f32x4 zf = {0.f, 0.f, 0.f, 0.f};
    f32x4 o[32];
    #pragma unroll
    for (int n = 0; n < 32; n++) o[n] = zf;
    float mrow[4], lrow[4];
    #pragma unroll
    for (int j = 0; j < 4; j++) { mrow[j] = -1e30f; lrow[j] = 0.0f; }

    const int g = lane >> 4;

    // staging helper (linear LDS dest, inverse-swizzled global src)
#define STAGE(BUF, KV0)                                                         \
    do {                                                                        \
        _Pragma("unroll")                                                       \
        for (int i = 0; i < 4; i++) {                                           \
            const int C   = i * 8192 + tid * 16;                                \
            const int row = C >> 10;                                            \
            const int Lc  = (C & 1023) ^ ((row & 7) << 4);                      \
            gl_lds16(k_ws + base + (size_t)((KV0) + row) * 512 + (Lc >> 1),     \
                     (char*)&k_lds[BUF][0] + C);                                \
        }                                                                       \
        _Pragma("unroll")                                                       \
        for (int i = 0; i < 4; i++) {                                           \
            const int C    = i * 8192 + tid * 16;                               \
            const int drow = C >> 6;                                            \
            const int gc   = (C >> 4) & 3;                                      \
            const int gl   = gc ^ ((drow >> 1) & 3);                            \
            gl_lds16(vt_ws + vbase + (size_t)drow * 4096 + (KV0) + gl * 8,      \
                     (char*)&vt_lds[BUF][0] + C);                               \
        }                                                                       \
    } while (0)

    // prologue
    STAGE(0, kv00);
    asm volatile("s_waitcnt vmcnt(0)" ::: "memory");
    __builtin_amdgcn_s_barrier();

    int cur = 0;
    for (int it = 0; it < NK; ++it) {
        if (it + 1 < NK) STAGE(cur ^ 1, kv00 + (it + 1) * 32);

        const char* kb = (const char*)&k_lds[cur][0];
        const char* vb = (const char*)&vt_lds[cur][0];

        // ---- QK^T : S[16 rows][32 keys]
        f32x4 s0 = zf, s1 = zf;
        #pragma unroll
        for (int ks = 0; ks < 16; ++ks) {
            const int key0 = lane & 15;
            const s16x8 kf0 = *reinterpret_cast<const s16x8*>(
                kb + key0 * 1024 + ((ks * 64 + g * 16) ^ ((key0 & 7) << 4)));
            s0 = mfma_bf16(qf[ks], kf0, s0);
            const int key1 = 16 + (lane & 15);
            const s16x8 kf1 = *reinterpret_cast<const s16x8*>(
                kb + key1 * 1024 + ((ks * 64 + g * 16) ^ ((key1 & 7) << 4)));
            s1 = mfma_bf16(qf[ks], kf1, s1);
        }

        // ---- tile max per row (16-lane group reduce)
        float pmax[4];
        #pragma unroll
        for (int j = 0; j < 4; j++) {
            float mt = fmaxf(s0[j], s1[j]);
            #pragma unroll
            for (int msk = 8; msk >= 1; msk >>= 1) mt = fmaxf(mt, __shfl_xor(mt, msk, 64));
            pmax[j] = mt;
        }

        // ---- deferred rescale (T13): only when max grows past threshold
        int need = 0;
        #pragma unroll
        for (int j = 0; j < 4; j++) need |= (pmax[j] > mrow[j] + DEFER_THR) ? 1 : 0;
        if (__any(need)) {
            #pragma unroll
            for (int j = 0; j < 4; j++) {
                const float mn = fmaxf(mrow[j], pmax[j]);
                const float fc = exp2f(mrow[j] - mn);
                mrow[j] = mn;
                lrow[j] *= fc;
                #pragma unroll
                for (int n = 0; n < 32; n++) o[n][j] *= fc;
            }
        }

        // ---- P = exp2(S - m), row-sum, stash to per-wave LDS bounce
        #pragma unroll
        for (int j = 0; j < 4; j++) {
            const float p0 = exp2f(s0[j] - mrow[j]);
            const float p1 = exp2f(s1[j] - mrow[j]);
            float rs = p0 + p1;
            #pragma unroll
            for (int msk = 8; msk >= 1; msk >>= 1) rs += __shfl_xor(rs, msk, 64);
            lrow[j] += rs;
            const int prow = g * 4 + j;
            p_lds[wave][prow][lane & 15] = f2bf(p0);
            p_lds[wave][prow][16 + (lane & 15)] = f2bf(p1);
        }

        const s16x8 pf = *reinterpret_cast<const s16x8*>(
            &p_lds[wave][lane & 15][g * 8]);

        // ---- PV: O[16][512] += P[16][32] @ V[32][512]
        #pragma unroll
        for (int n = 0; n < 32; n++) {
            const int d = n * 16 + (lane & 15);
            const s16x8 vf = *reinterpret_cast<const s16x8*>(
                vb + d * 64 + ((g * 16) ^ (((d >> 1) & 3) << 4)));
            o[n] = mfma_bf16(pf, vf, o[n]);
        }

        asm volatile("s_waitcnt vmcnt(0)" ::: "memory");
        __builtin_amdgcn_s_barrier();
        cur ^= 1;
    }
#undef STAGE

    // ---- epilogue
    if (opart != nullptr) {
        const int qrowb = qblk * 128 + wave * 16;
        const size_t prow8k = (size_t)batch * 4096;
        #pragma unroll
        for (int j = 0; j < 4; j++) {
            if ((lane & 15) == 0) {
                const size_t r8 = prow8k + qrowb + g * 4 + j;
                ml[((size_t)split * 8192 + r8) * 2]     = mrow[j];
                ml[((size_t)split * 8192 + r8) * 2 + 1] = lrow[j];
            }
        }
        ushort_t* op = opart + (size_t)split * 8192 * 512;
        #pragma unroll
        for (int n = 0; n < 32; n++) {
            #pragma unroll
            for (int j = 0; j < 4; j++) {
                const size_t r8 = prow8k + qrowb + g * 4 + j;
                op[r8 * 512 + n * 16 + (lane & 15)] = f2bf(o[n][j]);
            }
        }
    } else {
        float inv[4];
        #pragma unroll
        for (int j = 0; j < 4; j++) inv[j] = 1.0f / lrow[j];
        const int qrowb = qblk * 128 + wave * 16;
        #pragma unroll
        for (int n = 0; n < 32; n++) {
            #pragma unroll
            for (int j = 0; j < 4; j++) {
                const int row = qrowb + g * 4 + j;
                out[base + (size_t)row * 512 + n * 16 + (lane & 15)] = o[n][j] * inv[j];
            }
        }
    }
}

// ---------------------------------------------------------------------------
// Kernel 3: merge KV-split partials (exp2 domain). 1 wave/row, 4 rows/block.
// ---------------------------------------------------------------------------
__global__ __launch_bounds__(256) void merge_kernel(
    const ushort_t* __restrict__ opart, const float* __restrict__ ml,
    float* __restrict__ out, int SP)
{
    const int row  = blockIdx.x * 4 + (threadIdx.x >> 6);
    const int lane = threadIdx.x & 63;

    float M = -1e30f;
    for (int s = 0; s < SP; s++)
        M = fmaxf(M, ml[((size_t)s * 8192 + row) * 2]);
    float denom = 0.0f, w[4];
    for (int s = 0; s < SP; s++) {
        w[s] = exp2f(ml[((size_t)s * 8192 + row) * 2] - M);
        denom += w[s] * ml[((size_t)s * 8192 + row) * 2 + 1];
    }
    const float inv = 1.0f / denom;

    float acc[8] = {};
    for (int s = 0; s < SP; s++) {
        const s16x8 v = *reinterpret_cast<const s16x8*>(
            opart + ((size_t)s * 8192 + row) * 512 + lane * 8);
        #pragma unroll
        for (int i = 0; i < 8; i++)
            acc[i] += w[s] * bf2f((ushort_t)v[i]);
    }
    float* dst = out + (size_t)row * 512 + lane * 8;
    #pragma unroll
    for (int i = 0; i < 8; i++) dst[i] = acc[i] * inv;
}

extern "C" void kernel_launch(void* const* d_in, const int* in_sizes, int n_in,
                              void* d_out, int out_size, void* d_ws, size_t ws_size,
                              hipStream_t stream) {
    const float* x  = (const float*)d_in[0];
    const float* Wq = (const float*)d_in[1];
    const float* bq = (const float*)d_in[2];
    const float* Wk = (const float*)d_in[3];
    const float* bk = (const float*)d_in[4];
    const float* Wv = (const float*)d_in[5];
    const float* bv = (const float*)d_in[6];
    float* out = (float*)d_out;
    ushort_t* qkv = (ushort_t*)d_ws;  // q | k | vt, each 8192*512 bf16
    (void)in_sizes; (void)n_in; (void)out_size;

    const size_t qkv_bytes = 3ull * 8192 * 512 * 2;  // 25165824

    int SP = 0;
    if (ws_size >= qkv_bytes + 4ull * (8388608 + 65536)) SP = 4;
    else if (ws_size >= qkv_bytes + 2ull * (8388608 + 65536)) SP = 2;
    else if (ws_size >= qkv_bytes + 1ull * (8388608 + 65536)) SP = 1;

    dim3 gp(64, 4, 3);
    qkv_proj<<<gp, 256, 0, stream>>>(x, Wq, bq, Wk, bk, Wv, bv, qkv);

    if (SP > 0) {
        ushort_t* opart = qkv + 3ull * 8192 * 512;
        float* ml = (float*)(opart + (size_t)SP * 8192 * 512);
        dim3 ga(2 * SP, 32);
        attn_v3<<<ga, 512, 0, stream>>>(qkv, opart, ml, out, SP, (4096 / SP) / 32);
        merge_kernel<<<2048, 256, 0, stream>>>(opart, ml, out, SP);
    } else {
        dim3 ga(2, 32);
        attn_v3<<<ga, 512, 0, stream>>>(qkv, nullptr, nullptr, out, 1, 128);
    }
}